// Round 1
// baseline (1991.706 us; speedup 1.0000x reference)
//
#include <hip/hip_runtime.h>
#include <hip/hip_bf16.h>
#include <cstdint>
#include <cstddef>

typedef __bf16 bf16;
typedef __bf16 bf16x4 __attribute__((ext_vector_type(4)));
typedef __bf16 bf16x8 __attribute__((ext_vector_type(8)));
typedef float  f32x4  __attribute__((ext_vector_type(4)));

#define BL      8192
#define DDIM    1024
#define NSLOTS  32768
#define NSPLIT  8
#define SLOTS_PER (NSLOTS / NSPLIT)   // 4096
// CAP=17: 2*CAP%32==2 -> 2-way (free) drain reads; small enough that the
// double-buffered tiles + cand fit in <80KB (2 blocks/CU). Since 64-CAP > CAP,
// overflow rescan is a while-loop (terminates in <= ceil(64/CAP) passes,
// only triggered during warm-up chunks before thr is established).
#define CAP     17

// ---- workspace layout (bytes). Aliasing by lifetime.
#define WS_MN    ((size_t)0)                       // bf16 32768x1024 = 64 MB
#define WS_PRED  ((size_t)0)                       // f32 8192x1024 = 32 MB (alias)
#define WS_HBF   ((size_t)67108864)                // bf16 8192x1024 = 16 MB
#define WS_HMID  WS_HBF                            // alias
#define WS_WKT   ((size_t)83886080)                // bf16 1024x1024 = 2 MB
#define WS_W1T   ((size_t)85983232)                // bf16 1024x2048 = 4 MB
#define WS_KEYS  ((size_t)90177536)                // f32 8192x1024 = 32 MB
#define WS_FEATS WS_KEYS                           // bf16 8192x2048 = 32 MB (alias)
#define WS_KN    ((size_t)123731968)               // bf16 8192x1024 = 16 MB
#define WS_TPK   ((size_t)140509184)               // u32 8192x8x2x16 = 8 MB
#define WS_CONF  ((size_t)148897792)               // f32 8192

// ------------------------------------------------------------------
__device__ __forceinline__ void async16(const void* g, void* l) {
  __builtin_amdgcn_global_load_lds(
      (const __attribute__((address_space(1))) void*)g,
      (__attribute__((address_space(3))) void*)(uintptr_t)(uint32_t)(uintptr_t)l,
      16, 0, 0);
}

// stage a 128x32 bf16 tile (leading dim ld) into lds[128*32]; 2 loads/thread
__device__ __forceinline__ void stage_tile(const bf16* __restrict__ src, int ld,
                                           bf16* lds, int tid) {
  const int wave = tid >> 6;
#pragma unroll
  for (int issue = 0; issue < 2; ++issue) {
    const int gi  = issue * 256 + tid;   // 16B granule index, 0..511
    const int row = gi >> 2;
    const int gc  = gi & 3;
    const bf16* g = src + (size_t)row * ld + gc * 8;
    bf16* l = lds + (size_t)(issue * 256 + wave * 64) * 8;  // wave-uniform base
    async16(g, l);
  }
}

__device__ __forceinline__ f32x4 mfma_bf16(bf16x8 a, bf16x8 b, f32x4 c) {
  return __builtin_amdgcn_mfma_f32_16x16x32_bf16(a, b, c, 0, 0, 0);
}

__device__ __forceinline__ float block_sum(float v, float* red) {
#pragma unroll
  for (int off = 32; off > 0; off >>= 1) v += __shfl_xor(v, off, 64);
  const int tid = threadIdx.x;
  if ((tid & 63) == 0) red[tid >> 6] = v;
  __syncthreads();
  v = red[0] + red[1] + red[2] + red[3];
  __syncthreads();
  return v;
}

__device__ __forceinline__ uint32_t pack_key(float v, int slot) {
  // order-preserving for v>0; 17 value bits | 15 slot bits
  return ((__float_as_uint(v) ^ 0x80000000u) & 0xFFFF8000u) | (uint32_t)slot;
}

// owner lane (one row-half per lane) merges its LDS candidate list into tk[16]
__device__ __forceinline__ void drain_merge(uint32_t* cand, int* cnt, int rb_own,
                                            uint32_t (&tk)[16], float& thrF) {
  int n = cnt[rb_own];
  n = n > CAP ? CAP : n;
  for (int t = 0;; ++t) {
    if (!__any(t < n)) break;
    uint32_t cur = 0u;
    if (t < n) cur = cand[rb_own * CAP + t];
#pragma unroll
    for (int p = 0; p < 16; ++p) {
      const uint32_t old = tk[p];
      const uint32_t mx = old > cur ? old : cur;
      tk[p] = mx;
      cur = old > cur ? cur : old;
    }
  }
  cnt[rb_own] = 0;
  thrF = __uint_as_float((tk[15] & 0xFFFF8000u) ^ 0x80000000u);
}

// ------------------------------------------------------------------
__global__ void cvt_bf16_kernel(const float* __restrict__ in, bf16* __restrict__ out, int n4) {
  int i = blockIdx.x * blockDim.x + threadIdx.x;
  if (i >= n4) return;
  f32x4 v = *(const f32x4*)(in + (size_t)i * 4);
  bf16x4 o = {(bf16)v.x, (bf16)v.y, (bf16)v.z, (bf16)v.w};
  *(bf16x4*)(out + (size_t)i * 4) = o;
}

__global__ void transpose_f32_bf16(const float* __restrict__ in, bf16* __restrict__ out,
                                   int R, int C) {
  __shared__ float tile[32][33];
  const int c0 = blockIdx.x * 32, r0 = blockIdx.y * 32;
  for (int i = threadIdx.y; i < 32; i += 8)
    tile[i][threadIdx.x] = in[(size_t)(r0 + i) * C + c0 + threadIdx.x];
  __syncthreads();
  for (int i = threadIdx.y; i < 32; i += 8)
    out[(size_t)(c0 + i) * R + r0 + threadIdx.x] = (bf16)tile[threadIdx.x][i];
}

__global__ __launch_bounds__(256) void rownorm_kernel(const float* __restrict__ in,
                                                      bf16* __restrict__ out) {
  __shared__ float red[4];
  const int row = blockIdx.x, t = threadIdx.x;
  f32x4 v = *(const f32x4*)(in + (size_t)row * 1024 + t * 4);
  float sq = v.x * v.x + v.y * v.y + v.z * v.z + v.w * v.w;
  sq = block_sum(sq, red);
  float sc = rsqrtf(sq + 1e-8f);
  bf16x4 o = {(bf16)(v.x * sc), (bf16)(v.y * sc), (bf16)(v.z * sc), (bf16)(v.w * sc)};
  *(bf16x4*)(out + (size_t)row * 1024 + t * 4) = o;
}

// ------------------------------------------------------------------
// C = A @ B^T  (128x128 tile, BK=32).  EPI 0: fp32+bias.  EPI 1: silu gate -> bf16.
// Double-buffered LDS + counted vmcnt: stage tile T+1, wait only tile T's 4
// loads (vmcnt(4)), raw s_barrier (no vmcnt(0) drain in the loop).
template <int EPI>
__global__ __launch_bounds__(256, 2) void gemm_bt_kernel(
    const bf16* __restrict__ A, const bf16* __restrict__ Bm, int Kd,
    float* __restrict__ Cf, bf16* __restrict__ Cb,
    const float* __restrict__ bias, const float* __restrict__ conf,
    const float* __restrict__ w1c) {
  __shared__ bf16 As[2][128 * 32];
  __shared__ bf16 Bs[2][128 * 32];
  const int tid = threadIdx.x;
  const int lane = tid & 63, wave = tid >> 6;
  const int wr = (wave >> 1) * 64, wc = (wave & 1) * 64;
  const int m0 = blockIdx.x * 128, n0 = blockIdx.y * 128;
  const int ar = lane & 15, ak = (lane >> 4) * 8;

  f32x4 acc[4][4];
#pragma unroll
  for (int i = 0; i < 4; ++i)
#pragma unroll
    for (int j = 0; j < 4; ++j) acc[i][j] = (f32x4){0.f, 0.f, 0.f, 0.f};

  const int NT = Kd >> 5;
  stage_tile(A + (size_t)m0 * Kd, Kd, &As[0][0], tid);
  stage_tile(Bm + (size_t)n0 * Kd, Kd, &Bs[0][0], tid);

  for (int T = 0; T < NT; ++T) {
    const int cur = T & 1;
    if (T + 1 < NT) {
      stage_tile(A + (size_t)m0 * Kd + (T + 1) * 32, Kd, &As[cur ^ 1][0], tid);
      stage_tile(Bm + (size_t)n0 * Kd + (T + 1) * 32, Kd, &Bs[cur ^ 1][0], tid);
      asm volatile("s_waitcnt vmcnt(4)" ::: "memory");   // tile T landed; T+1 in flight
    } else {
      asm volatile("s_waitcnt vmcnt(0)" ::: "memory");
    }
    __builtin_amdgcn_s_barrier();
    __builtin_amdgcn_sched_barrier(0);
    const bf16* Ab = &As[cur][0];
    const bf16* Bb = &Bs[cur][0];
    bf16x8 af[4], bfr[4];
#pragma unroll
    for (int i = 0; i < 4; ++i)
      af[i] = *(const bf16x8*)(Ab + (wr + i * 16 + ar) * 32 + ak);
#pragma unroll
    for (int j = 0; j < 4; ++j)
      bfr[j] = *(const bf16x8*)(Bb + (wc + j * 16 + ar) * 32 + ak);
#pragma unroll
    for (int i = 0; i < 4; ++i)
#pragma unroll
      for (int j = 0; j < 4; ++j)
        acc[i][j] = mfma_bf16(af[i], bfr[j], acc[i][j]);
    asm volatile("s_waitcnt lgkmcnt(0)" ::: "memory");   // reads of buf[cur] done
    __builtin_amdgcn_s_barrier();                        // before T+2 overwrites it
  }

  const int mq = (lane >> 4) * 4, nq = lane & 15;
#pragma unroll
  for (int i = 0; i < 4; ++i)
#pragma unroll
    for (int j = 0; j < 4; ++j)
#pragma unroll
      for (int r = 0; r < 4; ++r) {
        const int m = m0 + wr + i * 16 + mq + r;
        const int n = n0 + wc + j * 16 + nq;
        float x = acc[i][j][r];
        if (EPI == 0) {
          Cf[(size_t)m * 1024 + n] = x + bias[n];
        } else {
          x += bias[n] + conf[m] * w1c[n];
          x = x / (1.f + expf(-x));   // silu
          Cb[(size_t)m * 1024 + n] = (bf16)x;
        }
      }
}

// ------------------------------------------------------------------
// sims = kn @ mn^T with register-direct top-16.
// Flattened 512-tile K-pipeline: double-buffered LDS (As/Bs0/Bs1), counted
// vmcnt(6) so tile T+1's 6 loads/thread stay in flight across both barriers
// (T4); the first tile of the NEXT it-chunk is already staged when the top-k
// scan runs, so scan VALU time hides load latency. Raw s_barrier everywhere —
// no vmcnt(0) drain inside the loop. Scan itself is barrier-free; candidate
// lists are wave-private. Overflow rescan loops until no list overflows.
__global__ __launch_bounds__(256, 2) void sims_topk_kernel(
    const bf16* __restrict__ kn, const bf16* __restrict__ mn,
    uint32_t* __restrict__ tpk) {
  __shared__ bf16 As[2][128 * 32];     // 16 KB
  __shared__ bf16 Bs0[2][128 * 32];    // 16 KB
  __shared__ bf16 Bs1[2][128 * 32];    // 16 KB
  __shared__ uint32_t cand[256 * CAP]; // 17 KB: 128 rows x 2 col-halves
  __shared__ int cnt[256];             // 1 KB   (total 66 KB -> 2 blocks/CU)

  const int tid = threadIdx.x;
  const int lane = tid & 63, wave = tid >> 6;
  const int wr = (wave >> 1) * 64;     // wave's row base (block-local)
  const int ch = wave & 1;             // wave's col-half of the 128-wide N-tile
  const int split = blockIdx.x;        // grid (8,64): linear%8==split -> XCD affinity
  const int m0 = blockIdx.y * 128;
  const int sbeg = split * SLOTS_PER;
  const int ar = lane & 15, ak = (lane >> 4) * 8;
  const int mq = (lane >> 4) * 4, nq = lane & 15;
  const int rb_own = (wr + lane) * 2 + ch;   // this lane's candidate list

  cnt[tid] = 0;   // ordered vs first scan by the many barriers before T=31

  uint32_t tk[16];
#pragma unroll
  for (int j = 0; j < 16; ++j) tk[j] = 0u;
  float thrF = __uint_as_float(0x80000000u);  // -0.0f: only positives push

  f32x4 acc[2][4][4];

  // T = it*32 + kk over 16 it-chunks x 32 k-steps
  auto stage3 = [&](int Tt, int b) {
    const int k0 = (Tt & 31) * 32;
    const int n0 = sbeg + (Tt >> 5) * 256;
    stage_tile(kn + (size_t)m0 * 1024 + k0, 1024, &As[b][0], tid);
    stage_tile(mn + (size_t)n0 * 1024 + k0, 1024, &Bs0[b][0], tid);
    stage_tile(mn + (size_t)(n0 + 128) * 1024 + k0, 1024, &Bs1[b][0], tid);
  };

  stage3(0, 0);

  for (int T = 0; T < 512; ++T) {
    const int cur = T & 1;
    if ((T & 31) == 0) {
#pragma unroll
      for (int c = 0; c < 2; ++c)
#pragma unroll
        for (int i = 0; i < 4; ++i)
#pragma unroll
          for (int j = 0; j < 4; ++j) acc[c][i][j] = (f32x4){0.f, 0.f, 0.f, 0.f};
    }

    if (T + 1 < 512) {
      stage3(T + 1, cur ^ 1);
      asm volatile("s_waitcnt vmcnt(6)" ::: "memory");   // tile T landed; T+1 in flight
    } else {
      asm volatile("s_waitcnt vmcnt(0)" ::: "memory");
    }
    __builtin_amdgcn_s_barrier();          // all waves' tile-T loads landed
    __builtin_amdgcn_sched_barrier(0);     // pin ds_reads below the barrier

    const bf16* Ab  = &As[cur][0];
    const bf16* B0b = &Bs0[cur][0];
    const bf16* B1b = &Bs1[cur][0];
    bf16x8 af[4], b0[4], b1[4];
#pragma unroll
    for (int i = 0; i < 4; ++i)
      af[i] = *(const bf16x8*)(Ab + (wr + i * 16 + ar) * 32 + ak);
#pragma unroll
    for (int j = 0; j < 4; ++j) {
      b0[j] = *(const bf16x8*)(B0b + (ch * 64 + j * 16 + ar) * 32 + ak);
      b1[j] = *(const bf16x8*)(B1b + (ch * 64 + j * 16 + ar) * 32 + ak);
    }
#pragma unroll
    for (int i = 0; i < 4; ++i)
#pragma unroll
      for (int j = 0; j < 4; ++j) {
        acc[0][i][j] = mfma_bf16(af[i], b0[j], acc[0][i][j]);
        acc[1][i][j] = mfma_bf16(af[i], b1[j], acc[1][i][j]);
      }
    asm volatile("s_waitcnt lgkmcnt(0)" ::: "memory");   // reads of buf[cur] done
    __builtin_amdgcn_s_barrier();                        // before T+2 overwrites it

    if ((T & 31) == 31) {
      // register-direct scan of both 128-slot chunks (no barriers)
      const int itn0 = sbeg + (T >> 5) * 256;
#pragma unroll
      for (int cc = 0; cc < 2; ++cc) {
        const int colbase = itn0 + cc * 128 + ch * 64;
        uint64_t skip = 0ull;
#pragma unroll
        for (int i = 0; i < 4; ++i)
#pragma unroll
          for (int r = 0; r < 4; ++r) {
            const int owner = i * 16 + mq + r;               // 0..63 (lane id)
            const float thr = __shfl(thrF, owner, 64);
            const int rb = (wr + owner) * 2 + ch;
#pragma unroll
            for (int j = 0; j < 4; ++j) {
              const float v = acc[cc][i][j][r];
              if (v > thr) {
                const int old = atomicAdd(&cnt[rb], 1);
                if (old < CAP) cand[rb * CAP + old] = pack_key(v, colbase + j * 16 + nq);
                else skip |= (1ull << (i * 16 + r * 4 + j));
              }
            }
          }
        drain_merge(cand, cnt, rb_own, tk, thrF);
        while (__any(skip != 0ull)) {   // overflow rescan: <= ceil(64/CAP) passes
          uint64_t ns = 0ull;
#pragma unroll
          for (int i = 0; i < 4; ++i)
#pragma unroll
            for (int r = 0; r < 4; ++r) {
              const int owner = i * 16 + mq + r;
              const float thr = __shfl(thrF, owner, 64);
              const int rb = (wr + owner) * 2 + ch;
#pragma unroll
              for (int j = 0; j < 4; ++j) {
                if (skip & (1ull << (i * 16 + r * 4 + j))) {
                  const float v = acc[cc][i][j][r];
                  if (v > thr) {
                    const int old = atomicAdd(&cnt[rb], 1);
                    if (old < CAP) cand[rb * CAP + old] = pack_key(v, colbase + j * 16 + nq);
                    else ns |= (1ull << (i * 16 + r * 4 + j));
                  }
                }
              }
            }
          drain_merge(cand, cnt, rb_own, tk, thrF);
          skip = ns;
        }
      }
    }
  }

  // emit: [row][split][half][16] -> 256 candidates per row
  const int row = m0 + wr + lane;
  uint32_t* dst = tpk + (((size_t)row * NSPLIT + split) * 2 + ch) * 16;
#pragma unroll
  for (int j = 0; j < 16; ++j) dst[j] = tk[j];
}

// ------------------------------------------------------------------
// merge 256 candidate keys -> top-16, softmax, weighted gather of vals
__global__ __launch_bounds__(256) void merge_pred_kernel(
    const uint32_t* __restrict__ tpk, const float* __restrict__ vals,
    float* __restrict__ pred, float* __restrict__ conf) {
  __shared__ uint32_t ks[256];
  __shared__ float sv[16];
  __shared__ int si[16];
  __shared__ float sw[16];
  const int row = blockIdx.x, t = threadIdx.x;
  const uint32_t k = tpk[(size_t)row * 256 + t];
  ks[t] = k;
  __syncthreads();
  int rank = 0;
  for (int j = 0; j < 256; ++j) rank += (ks[j] > k);   // keys unique (slot bits)
  if (rank < 16) {
    sv[rank] = __uint_as_float((k & 0xFFFF8000u) ^ 0x80000000u);
    si[rank] = (int)(k & 0x7FFFu);
  }
  __syncthreads();
  if (t == 0) {
    const float m = sv[0];
    float s = 0.f;
#pragma unroll
    for (int q = 0; q < 16; ++q) {
      float e = expf((sv[q] - m) * 10.f);   // 1/TEMP
      sw[q] = e;
      s += e;
    }
    const float inv = 1.f / s;
#pragma unroll
    for (int q = 0; q < 16; ++q) sw[q] *= inv;
    conf[row] = (m + 1.f) * 0.5f;
  }
  __syncthreads();
  const int col = t * 4;
  f32x4 a = (f32x4){0.f, 0.f, 0.f, 0.f};
#pragma unroll
  for (int q = 0; q < 16; ++q) {
    f32x4 vv = *(const f32x4*)(vals + (size_t)si[q] * 1024 + col);
    a += vv * sw[q];
  }
  *(f32x4*)(pred + (size_t)row * 1024 + col) = a;
}

// ------------------------------------------------------------------
__global__ __launch_bounds__(256) void feats_kernel(
    const float* __restrict__ h, const float* __restrict__ pred,
    const float* __restrict__ gin, const float* __restrict__ bin,
    const float* __restrict__ gpr, const float* __restrict__ bpr,
    bf16* __restrict__ feats) {
  __shared__ float red[4];
  const int row = blockIdx.x, t = threadIdx.x;
  {
    f32x4 v = *(const f32x4*)(h + (size_t)row * 1024 + t * 4);
    float s = v.x + v.y + v.z + v.w;
    float sq = v.x * v.x + v.y * v.y + v.z * v.z + v.w * v.w;
    s = block_sum(s, red);
    sq = block_sum(sq, red);
    const float mean = s * (1.f / 1024.f);
    const float rstd = rsqrtf(sq * (1.f / 1024.f) - mean * mean + 1e-5f);
    f32x4 g = *(const f32x4*)(gin + t * 4);
    f32x4 b = *(const f32x4*)(bin + t * 4);
    bf16x4 o = {(bf16)((v.x - mean) * rstd * g.x + b.x),
                (bf16)((v.y - mean) * rstd * g.y + b.y),
                (bf16)((v.z - mean) * rstd * g.z + b.z),
                (bf16)((v.w - mean) * rstd * g.w + b.w)};
    *(bf16x4*)(feats + (size_t)row * 2048 + t * 4) = o;
  }
  {
    f32x4 v = *(const f32x4*)(pred + (size_t)row * 1024 + t * 4);
    float s = v.x + v.y + v.z + v.w;
    float sq = v.x * v.x + v.y * v.y + v.z * v.z + v.w * v.w;
    s = block_sum(s, red);
    sq = block_sum(sq, red);
    const float mean = s * (1.f / 1024.f);
    const float rstd = rsqrtf(sq * (1.f / 1024.f) - mean * mean + 1e-5f);
    f32x4 g = *(const f32x4*)(gpr + t * 4);
    f32x4 b = *(const f32x4*)(bpr + t * 4);
    bf16x4 o = {(bf16)((v.x - mean) * rstd * g.x + b.x),
                (bf16)((v.y - mean) * rstd * g.y + b.y),
                (bf16)((v.z - mean) * rstd * g.z + b.z),
                (bf16)((v.w - mean) * rstd * g.w + b.w)};
    *(bf16x4*)(feats + (size_t)row * 2048 + 1024 + t * 4) = o;
  }
}

// ------------------------------------------------------------------
__global__ __launch_bounds__(256) void final_kernel(
    const bf16* __restrict__ hmid, const float* __restrict__ W2,
    const float* __restrict__ b2, const float* __restrict__ h,
    const float* __restrict__ pred, const float* __restrict__ conf,
    float* __restrict__ out) {
  __shared__ float red[4];
  const int row = blockIdx.x, t = threadIdx.x;
  float s = 0.f;
#pragma unroll
  for (int j = 0; j < 4; ++j) {
    const int c = t + 256 * j;
    s += (float)hmid[(size_t)row * 1024 + c] * W2[c];
  }
  s = block_sum(s, red);
  float alpha = 1.f / (1.f + expf(-(s + b2[0])));
  alpha = fminf(fmaxf(alpha, 0.f), 1.f);
  f32x4 hv = *(const f32x4*)(h + (size_t)row * 1024 + t * 4);
  f32x4 pv = *(const f32x4*)(pred + (size_t)row * 1024 + t * 4);
  f32x4 y = hv + pv * alpha;
  *(f32x4*)(out + (size_t)row * 1024 + t * 4) = y;
  if (t == 0) {
    atomicAdd(out + 8388608, alpha * (1.f / 8192.f));
    atomicAdd(out + 8388609, conf[row] * (1.f / 8192.f));
  }
}

// ------------------------------------------------------------------
extern "C" void kernel_launch(void* const* d_in, const int* in_sizes, int n_in,
                              void* d_out, int out_size, void* d_ws, size_t ws_size,
                              hipStream_t stream) {
  const float* h_in      = (const float*)d_in[0];
  const float* Wk        = (const float*)d_in[1];
  const float* bk        = (const float*)d_in[2];
  const float* cube_keys = (const float*)d_in[3];
  const float* cube_vals = (const float*)d_in[4];
  const float* ln_in_g   = (const float*)d_in[5];
  const float* ln_in_b   = (const float*)d_in[6];
  const float* ln_pred_g = (const float*)d_in[7];
  const float* ln_pred_b = (const float*)d_in[8];
  const float* W1        = (const float*)d_in[9];
  const float* b1        = (const float*)d_in[10];
  const float* W2        = (const float*)d_in[11];
  const float* b2        = (const float*)d_in[12];

  char* ws = (char*)d_ws;
  bf16*     mn    = (bf16*)(ws + WS_MN);
  float*    pred  = (float*)(ws + WS_PRED);
  bf16*     h_bf  = (bf16*)(ws + WS_HBF);
  bf16*     hmid  = (bf16*)(ws + WS_HMID);
  bf16*     wkT   = (bf16*)(ws + WS_WKT);
  bf16*     w1T   = (bf16*)(ws + WS_W1T);
  float*    keys  = (float*)(ws + WS_KEYS);
  bf16*     feats = (bf16*)(ws + WS_FEATS);
  bf16*     kn    = (bf16*)(ws + WS_KN);
  uint32_t* tpk   = (uint32_t*)(ws + WS_TPK);
  float*    conf  = (float*)(ws + WS_CONF);
  float*    out   = (float*)d_out;
  const float* w1c = W1 + (size_t)2048 * 1024;  // conf row of W1

  cvt_bf16_kernel<<<(BL * DDIM / 4 + 255) / 256, 256, 0, stream>>>(h_in, h_bf, BL * DDIM / 4);
  transpose_f32_bf16<<<dim3(32, 32), dim3(32, 8), 0, stream>>>(Wk, wkT, 1024, 1024);
  transpose_f32_bf16<<<dim3(32, 64), dim3(32, 8), 0, stream>>>(W1, w1T, 2048, 1024);
  rownorm_kernel<<<NSLOTS, 256, 0, stream>>>(cube_keys, mn);

  gemm_bt_kernel<0><<<dim3(64, 8), 256, 0, stream>>>(h_bf, wkT, 1024, keys, nullptr,
                                                     bk, nullptr, nullptr);
  rownorm_kernel<<<BL, 256, 0, stream>>>(keys, kn);

  // fused sims GEMM + register-direct top-16
  sims_topk_kernel<<<dim3(NSPLIT, 64), 256, 0, stream>>>(kn, mn, tpk);

  merge_pred_kernel<<<BL, 256, 0, stream>>>(tpk, cube_vals, pred, conf);

  feats_kernel<<<BL, 256, 0, stream>>>(h_in, pred, ln_in_g, ln_in_b,
                                       ln_pred_g, ln_pred_b, feats);
  gemm_bt_kernel<1><<<dim3(64, 8), 256, 0, stream>>>(feats, w1T, 2048, nullptr, hmid,
                                                     b1, conf, w1c);

  hipMemsetAsync(out + 8388608, 0, 8, stream);
  final_kernel<<<BL, 256, 0, stream>>>(hmid, W2, b2, h_in, pred, conf, out);
}

// Round 2
// 1762.007 us; speedup vs baseline: 1.1304x; 1.1304x over previous
//
#include <hip/hip_runtime.h>
#include <hip/hip_bf16.h>
#include <cstdint>
#include <cstddef>

typedef __bf16 bf16;
typedef __bf16 bf16x4 __attribute__((ext_vector_type(4)));
typedef __bf16 bf16x8 __attribute__((ext_vector_type(8)));
typedef float  f32x4  __attribute__((ext_vector_type(4)));

#define BL      8192
#define DDIM    1024
#define NSLOTS  32768
#define NSPLIT  8
#define SLOTS_PER (NSLOTS / NSPLIT)   // 4096
// CAP=17 (proven r1): dbuf tiles 48KB + cand 17KB + cnt 1KB = 66.9KB -> 2 blocks/CU.
// 64-CAP > CAP so overflow rescan is a while-loop (terminates, warm-up only).
#define CAP     17

// ---- workspace layout (bytes). Aliasing by lifetime.
#define WS_MN    ((size_t)0)                       // bf16 32768x1024 = 64 MB
#define WS_PRED  ((size_t)0)                       // f32 8192x1024 = 32 MB (alias)
#define WS_HBF   ((size_t)67108864)                // bf16 8192x1024 = 16 MB
#define WS_HMID  WS_HBF                            // alias
#define WS_WKT   ((size_t)83886080)                // bf16 1024x1024 = 2 MB
#define WS_W1T   ((size_t)85983232)                // bf16 1024x2048 = 4 MB
#define WS_KEYS  ((size_t)90177536)                // f32 8192x1024 = 32 MB
#define WS_FEATS WS_KEYS                           // bf16 8192x2048 = 32 MB (alias)
#define WS_KN    ((size_t)123731968)               // bf16 8192x1024 = 16 MB
#define WS_TPK   ((size_t)140509184)               // u32 8192x8x2x16 = 8 MB
#define WS_CONF  ((size_t)148897792)               // f32 8192

// ------------------------------------------------------------------
__device__ __forceinline__ void async16(const void* g, void* l) {
  __builtin_amdgcn_global_load_lds(
      (const __attribute__((address_space(1))) void*)g,
      (__attribute__((address_space(3))) void*)(uintptr_t)(uint32_t)(uintptr_t)l,
      16, 0, 0);
}

// stage a 128x32 bf16 tile into lds[128*32], XOR-swizzled (T2, both-sides rule):
// LDS dest is linear (global_load_lds requirement); the SOURCE chunk within each
// 64B row is permuted: LDS(row, c) holds global(row, c ^ ((row>>1)&3)).
// Reads apply the same involution. Global coalescing unchanged (permutation
// stays inside each 64B row segment).
__device__ __forceinline__ void stage_tile(const bf16* __restrict__ src, int ld,
                                           bf16* lds, int tid) {
  const int wave = tid >> 6;
#pragma unroll
  for (int issue = 0; issue < 2; ++issue) {
    const int gi  = issue * 256 + tid;   // 16B granule index, 0..511
    const int row = gi >> 2;
    const int gc  = (gi & 3) ^ ((gi >> 3) & 3);   // pre-swizzled source chunk
    const bf16* g = src + (size_t)row * ld + gc * 8;
    bf16* l = lds + (size_t)(issue * 256 + wave * 64) * 8;  // wave-uniform base
    async16(g, l);
  }
}

__device__ __forceinline__ f32x4 mfma_bf16(bf16x8 a, bf16x8 b, f32x4 c) {
  return __builtin_amdgcn_mfma_f32_16x16x32_bf16(a, b, c, 0, 0, 0);
}

__device__ __forceinline__ float block_sum(float v, float* red) {
#pragma unroll
  for (int off = 32; off > 0; off >>= 1) v += __shfl_xor(v, off, 64);
  const int tid = threadIdx.x;
  if ((tid & 63) == 0) red[tid >> 6] = v;
  __syncthreads();
  v = red[0] + red[1] + red[2] + red[3];
  __syncthreads();
  return v;
}

__device__ __forceinline__ uint32_t pack_key(float v, int slot) {
  // order-preserving for v>0; 17 value bits | 15 slot bits
  return ((__float_as_uint(v) ^ 0x80000000u) & 0xFFFF8000u) | (uint32_t)slot;
}

// owner lane (one row-half per lane) merges its LDS candidate list into tk[16]
__device__ __forceinline__ void drain_merge(uint32_t* cand, int* cnt, int rb_own,
                                            uint32_t (&tk)[16], float& thrF) {
  int n = cnt[rb_own];
  n = n > CAP ? CAP : n;
  for (int t = 0;; ++t) {
    if (!__any(t < n)) break;
    uint32_t cur = 0u;
    if (t < n) cur = cand[rb_own * CAP + t];
#pragma unroll
    for (int p = 0; p < 16; ++p) {
      const uint32_t old = tk[p];
      const uint32_t mx = old > cur ? old : cur;
      tk[p] = mx;
      cur = old > cur ? cur : old;
    }
  }
  cnt[rb_own] = 0;
  thrF = __uint_as_float((tk[15] & 0xFFFF8000u) ^ 0x80000000u);
}

// ------------------------------------------------------------------
__global__ void cvt_bf16_kernel(const float* __restrict__ in, bf16* __restrict__ out, int n4) {
  int i = blockIdx.x * blockDim.x + threadIdx.x;
  if (i >= n4) return;
  f32x4 v = *(const f32x4*)(in + (size_t)i * 4);
  bf16x4 o = {(bf16)v.x, (bf16)v.y, (bf16)v.z, (bf16)v.w};
  *(bf16x4*)(out + (size_t)i * 4) = o;
}

__global__ void transpose_f32_bf16(const float* __restrict__ in, bf16* __restrict__ out,
                                   int R, int C) {
  __shared__ float tile[32][33];
  const int c0 = blockIdx.x * 32, r0 = blockIdx.y * 32;
  for (int i = threadIdx.y; i < 32; i += 8)
    tile[i][threadIdx.x] = in[(size_t)(r0 + i) * C + c0 + threadIdx.x];
  __syncthreads();
  for (int i = threadIdx.y; i < 32; i += 8)
    out[(size_t)(c0 + i) * R + r0 + threadIdx.x] = (bf16)tile[threadIdx.x][i];
}

__global__ __launch_bounds__(256) void rownorm_kernel(const float* __restrict__ in,
                                                      bf16* __restrict__ out) {
  __shared__ float red[4];
  const int row = blockIdx.x, t = threadIdx.x;
  f32x4 v = *(const f32x4*)(in + (size_t)row * 1024 + t * 4);
  float sq = v.x * v.x + v.y * v.y + v.z * v.z + v.w * v.w;
  sq = block_sum(sq, red);
  float sc = rsqrtf(sq + 1e-8f);
  bf16x4 o = {(bf16)(v.x * sc), (bf16)(v.y * sc), (bf16)(v.z * sc), (bf16)(v.w * sc)};
  *(bf16x4*)(out + (size_t)row * 1024 + t * 4) = o;
}

// ------------------------------------------------------------------
// C = A @ B^T  (128x128 tile, BK=32).  EPI 0: fp32+bias.  EPI 1: silu gate -> bf16.
// Double-buffered LDS + counted vmcnt(4); swizzled stage/read (see stage_tile).
template <int EPI>
__global__ __launch_bounds__(256, 2) void gemm_bt_kernel(
    const bf16* __restrict__ A, const bf16* __restrict__ Bm, int Kd,
    float* __restrict__ Cf, bf16* __restrict__ Cb,
    const float* __restrict__ bias, const float* __restrict__ conf,
    const float* __restrict__ w1c) {
  __shared__ bf16 As0[128 * 32];
  __shared__ bf16 As1[128 * 32];
  __shared__ bf16 Bs0[128 * 32];
  __shared__ bf16 Bs1[128 * 32];
  const int tid = threadIdx.x;
  const int lane = tid & 63, wave = tid >> 6;
  const int wr = (wave >> 1) * 64, wc = (wave & 1) * 64;
  const int m0 = blockIdx.x * 128, n0 = blockIdx.y * 128;
  const int ar = lane & 15;
  const int sw8 = (((lane >> 4) ^ ((ar >> 1) & 3)) << 3);  // swizzled chunk, elems

  f32x4 acc[4][4];
#pragma unroll
  for (int i = 0; i < 4; ++i)
#pragma unroll
    for (int j = 0; j < 4; ++j) acc[i][j] = (f32x4){0.f, 0.f, 0.f, 0.f};

  const bf16 *Ac = As0, *An = As1, *Bc = Bs0, *Bn = Bs1;
  const int NT = Kd >> 5;
  stage_tile(A + (size_t)m0 * Kd, Kd, (bf16*)Ac, tid);
  stage_tile(Bm + (size_t)n0 * Kd, Kd, (bf16*)Bc, tid);

  for (int T = 0; T < NT; ++T) {
    if (T + 1 < NT) {
      stage_tile(A + (size_t)m0 * Kd + (T + 1) * 32, Kd, (bf16*)An, tid);
      stage_tile(Bm + (size_t)n0 * Kd + (T + 1) * 32, Kd, (bf16*)Bn, tid);
      asm volatile("s_waitcnt vmcnt(4)" ::: "memory");   // tile T landed; T+1 in flight
    } else {
      asm volatile("s_waitcnt vmcnt(0)" ::: "memory");
    }
    __builtin_amdgcn_s_barrier();
    bf16x8 af[4], bfr[4];
#pragma unroll
    for (int i = 0; i < 4; ++i)
      af[i] = *(const bf16x8*)(Ac + (wr + i * 16 + ar) * 32 + sw8);
#pragma unroll
    for (int j = 0; j < 4; ++j)
      bfr[j] = *(const bf16x8*)(Bc + (wc + j * 16 + ar) * 32 + sw8);
#pragma unroll
    for (int i = 0; i < 4; ++i)
#pragma unroll
      for (int j = 0; j < 4; ++j)
        acc[i][j] = mfma_bf16(af[i], bfr[j], acc[i][j]);
    asm volatile("s_waitcnt lgkmcnt(0)" ::: "memory");   // reads of cur buf done
    __builtin_amdgcn_s_barrier();                        // before T+2 overwrites it
    const bf16* t0 = Ac; Ac = An; An = t0;
    const bf16* t1 = Bc; Bc = Bn; Bn = t1;
  }

  const int mq = (lane >> 4) * 4, nq = lane & 15;
#pragma unroll
  for (int i = 0; i < 4; ++i)
#pragma unroll
    for (int j = 0; j < 4; ++j)
#pragma unroll
      for (int r = 0; r < 4; ++r) {
        const int m = m0 + wr + i * 16 + mq + r;
        const int n = n0 + wc + j * 16 + nq;
        float x = acc[i][j][r];
        if (EPI == 0) {
          Cf[(size_t)m * 1024 + n] = x + bias[n];
        } else {
          x += bias[n] + conf[m] * w1c[n];
          x = x / (1.f + expf(-x));   // silu
          Cb[(size_t)m * 1024 + n] = (bf16)x;
        }
      }
}

// ------------------------------------------------------------------
// sims = kn @ mn^T with register-direct top-16.
// Round-0 nesting (scan OUTSIDE the k-loop: register-max point has no pipeline
// state live -> no spill) + dbuf/counted-vmcnt k-loop (T3-min/T4): stage tile
// k+1, s_waitcnt vmcnt(6) (tile k landed, k+1 in flight across both barriers),
// raw s_barrier. At kk=31 the NEXT chunk's first tile is prefetched so the
// top-k scan's VALU time hides those loads. Swizzled stage/read kills the
// 8-way LDS read bank conflict (5.6e7 extra cycles in r0).
__global__ __launch_bounds__(256, 2) void sims_topk_kernel(
    const bf16* __restrict__ kn, const bf16* __restrict__ mn,
    uint32_t* __restrict__ tpk) {
  __shared__ bf16 As0[128 * 32];       // 8 KB x6 = 48 KB
  __shared__ bf16 As1[128 * 32];
  __shared__ bf16 Bs00[128 * 32];
  __shared__ bf16 Bs01[128 * 32];
  __shared__ bf16 Bs10[128 * 32];
  __shared__ bf16 Bs11[128 * 32];
  __shared__ uint32_t cand[256 * CAP]; // 17 KB: 128 rows x 2 col-halves
  __shared__ int cnt[256];             // 1 KB   (total 66.9 KB -> 2 blocks/CU)

  const int tid = threadIdx.x;
  const int lane = tid & 63, wave = tid >> 6;
  const int wr = (wave >> 1) * 64;     // wave's row base (block-local)
  const int ch = wave & 1;             // wave's col-half of the 128-wide N-tile
  const int split = blockIdx.x;        // grid (8,64): linear%8==split -> XCD affinity
  const int m0 = blockIdx.y * 128;
  const int sbeg = split * SLOTS_PER;
  const int ar = lane & 15;
  const int sw8 = (((lane >> 4) ^ ((ar >> 1) & 3)) << 3);  // swizzled chunk, elems
  const int mq = (lane >> 4) * 4, nq = lane & 15;
  const int rb_own = (wr + lane) * 2 + ch;   // this lane's candidate list

  cnt[tid] = 0;   // ordered vs first scan by the 64 barriers of the first chunk

  uint32_t tk[16];
#pragma unroll
  for (int j = 0; j < 16; ++j) tk[j] = 0u;
  float thrF = __uint_as_float(0x80000000u);  // -0.0f: only positives push

  const bf16 *Ac = As0, *An = As1;
  const bf16 *P0c = Bs00, *P0n = Bs01;
  const bf16 *P1c = Bs10, *P1n = Bs11;

  // prologue: first tile of chunk 0
  stage_tile(kn + (size_t)m0 * 1024, 1024, (bf16*)Ac, tid);
  stage_tile(mn + (size_t)sbeg * 1024, 1024, (bf16*)P0c, tid);
  stage_tile(mn + (size_t)(sbeg + 128) * 1024, 1024, (bf16*)P1c, tid);

  for (int it = 0; it < 16; ++it) {
    const int n0 = sbeg + it * 256;
    f32x4 acc[2][4][4];
#pragma unroll
    for (int c = 0; c < 2; ++c)
#pragma unroll
      for (int i = 0; i < 4; ++i)
#pragma unroll
        for (int j = 0; j < 4; ++j) acc[c][i][j] = (f32x4){0.f, 0.f, 0.f, 0.f};

    for (int kk = 0; kk < 32; ++kk) {
      if (kk < 31) {
        const int k1 = (kk + 1) * 32;
        stage_tile(kn + (size_t)m0 * 1024 + k1, 1024, (bf16*)An, tid);
        stage_tile(mn + (size_t)n0 * 1024 + k1, 1024, (bf16*)P0n, tid);
        stage_tile(mn + (size_t)(n0 + 128) * 1024 + k1, 1024, (bf16*)P1n, tid);
        asm volatile("s_waitcnt vmcnt(6)" ::: "memory");
      } else if (it + 1 < 16) {
        // cross-chunk prefetch: next chunk's k=0 tile; lands under the scan
        stage_tile(kn + (size_t)m0 * 1024, 1024, (bf16*)An, tid);
        stage_tile(mn + (size_t)(n0 + 256) * 1024, 1024, (bf16*)P0n, tid);
        stage_tile(mn + (size_t)(n0 + 384) * 1024, 1024, (bf16*)P1n, tid);
        asm volatile("s_waitcnt vmcnt(6)" ::: "memory");
      } else {
        asm volatile("s_waitcnt vmcnt(0)" ::: "memory");
      }
      __builtin_amdgcn_s_barrier();     // all waves' current-tile loads landed

      bf16x8 af[4], b0[4], b1[4];
#pragma unroll
      for (int i = 0; i < 4; ++i)
        af[i] = *(const bf16x8*)(Ac + (wr + i * 16 + ar) * 32 + sw8);
#pragma unroll
      for (int j = 0; j < 4; ++j) {
        b0[j] = *(const bf16x8*)(P0c + (ch * 64 + j * 16 + ar) * 32 + sw8);
        b1[j] = *(const bf16x8*)(P1c + (ch * 64 + j * 16 + ar) * 32 + sw8);
      }
#pragma unroll
      for (int i = 0; i < 4; ++i)
#pragma unroll
        for (int j = 0; j < 4; ++j) {
          acc[0][i][j] = mfma_bf16(af[i], b0[j], acc[0][i][j]);
          acc[1][i][j] = mfma_bf16(af[i], b1[j], acc[1][i][j]);
        }
      asm volatile("s_waitcnt lgkmcnt(0)" ::: "memory");  // cur-buf reads done
      __builtin_amdgcn_s_barrier();                       // before next overwrite
      const bf16* t0 = Ac;  Ac  = An;  An  = t0;
      const bf16* t1 = P0c; P0c = P0n; P0n = t1;
      const bf16* t2 = P1c; P1c = P1n; P1n = t2;
    }
    // after 32 swaps, cur/nxt parity is back where it started; the cross-chunk
    // prefetch sits in the "nxt-at-kk31" buffer which is cur for kk=0 next chunk.

    // register-direct scan of both 128-slot chunks (no barriers; lists are
    // wave-private: rb uses this wave's wr/ch only)
#pragma unroll
    for (int cc = 0; cc < 2; ++cc) {
      const int colbase = n0 + cc * 128 + ch * 64;
      uint64_t skip = 0ull;
#pragma unroll
      for (int i = 0; i < 4; ++i)
#pragma unroll
        for (int r = 0; r < 4; ++r) {
          const int owner = i * 16 + mq + r;               // 0..63 (lane id)
          const float thr = __shfl(thrF, owner, 64);
          const int rb = (wr + owner) * 2 + ch;
#pragma unroll
          for (int j = 0; j < 4; ++j) {
            const float v = acc[cc][i][j][r];
            if (v > thr) {
              const int old = atomicAdd(&cnt[rb], 1);
              if (old < CAP) cand[rb * CAP + old] = pack_key(v, colbase + j * 16 + nq);
              else skip |= (1ull << (i * 16 + r * 4 + j));
            }
          }
        }
      drain_merge(cand, cnt, rb_own, tk, thrF);
      while (__any(skip != 0ull)) {   // overflow rescan (warm-up only)
        uint64_t ns = 0ull;
#pragma unroll
        for (int i = 0; i < 4; ++i)
#pragma unroll
          for (int r = 0; r < 4; ++r) {
            const int owner = i * 16 + mq + r;
            const float thr = __shfl(thrF, owner, 64);
            const int rb = (wr + owner) * 2 + ch;
#pragma unroll
            for (int j = 0; j < 4; ++j) {
              if (skip & (1ull << (i * 16 + r * 4 + j))) {
                const float v = acc[cc][i][j][r];
                if (v > thr) {
                  const int old = atomicAdd(&cnt[rb], 1);
                  if (old < CAP) cand[rb * CAP + old] = pack_key(v, colbase + j * 16 + nq);
                  else ns |= (1ull << (i * 16 + r * 4 + j));
                }
              }
            }
          }
        drain_merge(cand, cnt, rb_own, tk, thrF);
        skip = ns;
      }
    }
  }

  // emit: [row][split][half][16] -> 256 candidates per row
  const int row = m0 + wr + lane;
  uint32_t* dst = tpk + (((size_t)row * NSPLIT + split) * 2 + ch) * 16;
#pragma unroll
  for (int j = 0; j < 16; ++j) dst[j] = tk[j];
}

// ------------------------------------------------------------------
// merge 256 candidate keys -> top-16, softmax, weighted gather of vals
__global__ __launch_bounds__(256) void merge_pred_kernel(
    const uint32_t* __restrict__ tpk, const float* __restrict__ vals,
    float* __restrict__ pred, float* __restrict__ conf) {
  __shared__ uint32_t ks[256];
  __shared__ float sv[16];
  __shared__ int si[16];
  __shared__ float sw[16];
  const int row = blockIdx.x, t = threadIdx.x;
  const uint32_t k = tpk[(size_t)row * 256 + t];
  ks[t] = k;
  __syncthreads();
  int rank = 0;
  for (int j = 0; j < 256; ++j) rank += (ks[j] > k);   // keys unique (slot bits)
  if (rank < 16) {
    sv[rank] = __uint_as_float((k & 0xFFFF8000u) ^ 0x80000000u);
    si[rank] = (int)(k & 0x7FFFu);
  }
  __syncthreads();
  if (t == 0) {
    const float m = sv[0];
    float s = 0.f;
#pragma unroll
    for (int q = 0; q < 16; ++q) {
      float e = expf((sv[q] - m) * 10.f);   // 1/TEMP
      sw[q] = e;
      s += e;
    }
    const float inv = 1.f / s;
#pragma unroll
    for (int q = 0; q < 16; ++q) sw[q] *= inv;
    conf[row] = (m + 1.f) * 0.5f;
  }
  __syncthreads();
  const int col = t * 4;
  f32x4 a = (f32x4){0.f, 0.f, 0.f, 0.f};
#pragma unroll
  for (int q = 0; q < 16; ++q) {
    f32x4 vv = *(const f32x4*)(vals + (size_t)si[q] * 1024 + col);
    a += vv * sw[q];
  }
  *(f32x4*)(pred + (size_t)row * 1024 + col) = a;
}

// ------------------------------------------------------------------
__global__ __launch_bounds__(256) void feats_kernel(
    const float* __restrict__ h, const float* __restrict__ pred,
    const float* __restrict__ gin, const float* __restrict__ bin,
    const float* __restrict__ gpr, const float* __restrict__ bpr,
    bf16* __restrict__ feats) {
  __shared__ float red[4];
  const int row = blockIdx.x, t = threadIdx.x;
  {
    f32x4 v = *(const f32x4*)(h + (size_t)row * 1024 + t * 4);
    float s = v.x + v.y + v.z + v.w;
    float sq = v.x * v.x + v.y * v.y + v.z * v.z + v.w * v.w;
    s = block_sum(s, red);
    sq = block_sum(sq, red);
    const float mean = s * (1.f / 1024.f);
    const float rstd = rsqrtf(sq * (1.f / 1024.f) - mean * mean + 1e-5f);
    f32x4 g = *(const f32x4*)(gin + t * 4);
    f32x4 b = *(const f32x4*)(bin + t * 4);
    bf16x4 o = {(bf16)((v.x - mean) * rstd * g.x + b.x),
                (bf16)((v.y - mean) * rstd * g.y + b.y),
                (bf16)((v.z - mean) * rstd * g.z + b.z),
                (bf16)((v.w - mean) * rstd * g.w + b.w)};
    *(bf16x4*)(feats + (size_t)row * 2048 + t * 4) = o;
  }
  {
    f32x4 v = *(const f32x4*)(pred + (size_t)row * 1024 + t * 4);
    float s = v.x + v.y + v.z + v.w;
    float sq = v.x * v.x + v.y * v.y + v.z * v.z + v.w * v.w;
    s = block_sum(s, red);
    sq = block_sum(sq, red);
    const float mean = s * (1.f / 1024.f);
    const float rstd = rsqrtf(sq * (1.f / 1024.f) - mean * mean + 1e-5f);
    f32x4 g = *(const f32x4*)(gpr + t * 4);
    f32x4 b = *(const f32x4*)(bpr + t * 4);
    bf16x4 o = {(bf16)((v.x - mean) * rstd * g.x + b.x),
                (bf16)((v.y - mean) * rstd * g.y + b.y),
                (bf16)((v.z - mean) * rstd * g.z + b.z),
                (bf16)((v.w - mean) * rstd * g.w + b.w)};
    *(bf16x4*)(feats + (size_t)row * 2048 + 1024 + t * 4) = o;
  }
}

// ------------------------------------------------------------------
__global__ __launch_bounds__(256) void final_kernel(
    const bf16* __restrict__ hmid, const float* __restrict__ W2,
    const float* __restrict__ b2, const float* __restrict__ h,
    const float* __restrict__ pred, const float* __restrict__ conf,
    float* __restrict__ out) {
  __shared__ float red[4];
  const int row = blockIdx.x, t = threadIdx.x;
  float s = 0.f;
#pragma unroll
  for (int j = 0; j < 4; ++j) {
    const int c = t + 256 * j;
    s += (float)hmid[(size_t)row * 1024 + c] * W2[c];
  }
  s = block_sum(s, red);
  float alpha = 1.f / (1.f + expf(-(s + b2[0])));
  alpha = fminf(fmaxf(alpha, 0.f), 1.f);
  f32x4 hv = *(const f32x4*)(h + (size_t)row * 1024 + t * 4);
  f32x4 pv = *(const f32x4*)(pred + (size_t)row * 1024 + t * 4);
  f32x4 y = hv + pv * alpha;
  *(f32x4*)(out + (size_t)row * 1024 + t * 4) = y;
  if (t == 0) {
    atomicAdd(out + 8388608, alpha * (1.f / 8192.f));
    atomicAdd(out + 8388609, conf[row] * (1.f / 8192.f));
  }
}

// ------------------------------------------------------------------
extern "C" void kernel_launch(void* const* d_in, const int* in_sizes, int n_in,
                              void* d_out, int out_size, void* d_ws, size_t ws_size,
                              hipStream_t stream) {
  const float* h_in      = (const float*)d_in[0];
  const float* Wk        = (const float*)d_in[1];
  const float* bk        = (const float*)d_in[2];
  const float* cube_keys = (const float*)d_in[3];
  const float* cube_vals = (const float*)d_in[4];
  const float* ln_in_g   = (const float*)d_in[5];
  const float* ln_in_b   = (const float*)d_in[6];
  const float* ln_pred_g = (const float*)d_in[7];
  const float* ln_pred_b = (const float*)d_in[8];
  const float* W1        = (const float*)d_in[9];
  const float* b1        = (const float*)d_in[10];
  const float* W2        = (const float*)d_in[11];
  const float* b2        = (const float*)d_in[12];

  char* ws = (char*)d_ws;
  bf16*     mn    = (bf16*)(ws + WS_MN);
  float*    pred  = (float*)(ws + WS_PRED);
  bf16*     h_bf  = (bf16*)(ws + WS_HBF);
  bf16*     hmid  = (bf16*)(ws + WS_HMID);
  bf16*     wkT   = (bf16*)(ws + WS_WKT);
  bf16*     w1T   = (bf16*)(ws + WS_W1T);
  float*    keys  = (float*)(ws + WS_KEYS);
  bf16*     feats = (bf16*)(ws + WS_FEATS);
  bf16*     kn    = (bf16*)(ws + WS_KN);
  uint32_t* tpk   = (uint32_t*)(ws + WS_TPK);
  float*    conf  = (float*)(ws + WS_CONF);
  float*    out   = (float*)d_out;
  const float* w1c = W1 + (size_t)2048 * 1024;  // conf row of W1

  cvt_bf16_kernel<<<(BL * DDIM / 4 + 255) / 256, 256, 0, stream>>>(h_in, h_bf, BL * DDIM / 4);
  transpose_f32_bf16<<<dim3(32, 32), dim3(32, 8), 0, stream>>>(Wk, wkT, 1024, 1024);
  transpose_f32_bf16<<<dim3(32, 64), dim3(32, 8), 0, stream>>>(W1, w1T, 2048, 1024);
  rownorm_kernel<<<NSLOTS, 256, 0, stream>>>(cube_keys, mn);

  gemm_bt_kernel<0><<<dim3(64, 8), 256, 0, stream>>>(h_bf, wkT, 1024, keys, nullptr,
                                                     bk, nullptr, nullptr);
  rownorm_kernel<<<BL, 256, 0, stream>>>(keys, kn);

  // fused sims GEMM + register-direct top-16
  sims_topk_kernel<<<dim3(NSPLIT, 64), 256, 0, stream>>>(kn, mn, tpk);

  merge_pred_kernel<<<BL, 256, 0, stream>>>(tpk, cube_vals, pred, conf);

  feats_kernel<<<BL, 256, 0, stream>>>(h_in, pred, ln_in_g, ln_in_b,
                                       ln_pred_g, ln_pred_b, feats);
  gemm_bt_kernel<1><<<dim3(64, 8), 256, 0, stream>>>(feats, w1T, 2048, nullptr, hmid,
                                                     b1, conf, w1c);

  hipMemsetAsync(out + 8388608, 0, 8, stream);
  final_kernel<<<BL, 256, 0, stream>>>(hmid, W2, b2, h_in, pred, conf, out);
}

// Round 3
// 1405.690 us; speedup vs baseline: 1.4169x; 1.2535x over previous
//
#include <hip/hip_runtime.h>
#include <hip/hip_bf16.h>
#include <cstdint>
#include <cstddef>

typedef __bf16 bf16;
typedef __bf16 bf16x4 __attribute__((ext_vector_type(4)));
typedef __bf16 bf16x8 __attribute__((ext_vector_type(8)));
typedef float  f32x4  __attribute__((ext_vector_type(4)));

#define BL      8192
#define DDIM    1024
#define NSLOTS  32768
#define NSPLIT  8
#define SLOTS_PER (NSLOTS / NSPLIT)   // 4096
#define CAP     49                    // r0 value: 2*CAP%32==2 -> 2-way (free) drain reads

// ---- workspace layout (bytes). Aliasing by lifetime.
#define WS_MN    ((size_t)0)                       // bf16 32768x1024 = 64 MB
#define WS_PRED  ((size_t)0)                       // f32 8192x1024 = 32 MB (alias)
#define WS_HBF   ((size_t)67108864)                // bf16 8192x1024 = 16 MB
#define WS_HMID  WS_HBF                            // alias
#define WS_WKT   ((size_t)83886080)                // bf16 1024x1024 = 2 MB
#define WS_W1T   ((size_t)85983232)                // bf16 1024x2048 = 4 MB
#define WS_KEYS  ((size_t)90177536)                // f32 8192x1024 = 32 MB
#define WS_FEATS WS_KEYS                           // bf16 8192x2048 = 32 MB (alias)
#define WS_KN    ((size_t)123731968)               // bf16 8192x1024 = 16 MB
#define WS_TPK   ((size_t)140509184)               // u32 8192x8x2x16 = 8 MB
#define WS_CONF  ((size_t)148897792)               // f32 8192

// ------------------------------------------------------------------
__device__ __forceinline__ void async16(const void* g, void* l) {
  __builtin_amdgcn_global_load_lds(
      (const __attribute__((address_space(1))) void*)g,
      (__attribute__((address_space(3))) void*)(uintptr_t)(uint32_t)(uintptr_t)l,
      16, 0, 0);
}

// stage a 128x32 bf16 tile into lds[128*32], XOR-swizzled (T2, both-sides rule,
// validated r2: bank conflicts 5.6e7 -> 6.6e6). LDS dest is linear
// (global_load_lds requirement); the SOURCE 16B chunk within each 64B row is
// permuted: LDS(row, c) holds global(row, c ^ ((row>>1)&3)). Reads apply the
// same involution. Global coalescing unchanged (permutation stays inside each
// 64B row segment).
__device__ __forceinline__ void stage_tile(const bf16* __restrict__ src, int ld,
                                           bf16* lds, int tid) {
  const int wave = tid >> 6;
#pragma unroll
  for (int issue = 0; issue < 2; ++issue) {
    const int gi  = issue * 256 + tid;   // 16B granule index, 0..511
    const int row = gi >> 2;
    const int gc  = (gi & 3) ^ ((gi >> 3) & 3);   // pre-swizzled source chunk
    const bf16* g = src + (size_t)row * ld + gc * 8;
    bf16* l = lds + (size_t)(issue * 256 + wave * 64) * 8;  // wave-uniform base
    async16(g, l);
  }
}

__device__ __forceinline__ f32x4 mfma_bf16(bf16x8 a, bf16x8 b, f32x4 c) {
  return __builtin_amdgcn_mfma_f32_16x16x32_bf16(a, b, c, 0, 0, 0);
}

__device__ __forceinline__ float block_sum(float v, float* red) {
#pragma unroll
  for (int off = 32; off > 0; off >>= 1) v += __shfl_xor(v, off, 64);
  const int tid = threadIdx.x;
  if ((tid & 63) == 0) red[tid >> 6] = v;
  __syncthreads();
  v = red[0] + red[1] + red[2] + red[3];
  __syncthreads();
  return v;
}

__device__ __forceinline__ uint32_t pack_key(float v, int slot) {
  // order-preserving for v>0; 17 value bits | 15 slot bits
  return ((__float_as_uint(v) ^ 0x80000000u) & 0xFFFF8000u) | (uint32_t)slot;
}

// owner lane (one row-half per lane) merges its LDS candidate list into tk[16]
__device__ __forceinline__ void drain_merge(uint32_t* cand, int* cnt, int rb_own,
                                            uint32_t (&tk)[16], float& thrF) {
  int n = cnt[rb_own];
  n = n > CAP ? CAP : n;
  for (int t = 0;; ++t) {
    if (!__any(t < n)) break;
    uint32_t cur = 0u;
    if (t < n) cur = cand[rb_own * CAP + t];
#pragma unroll
    for (int p = 0; p < 16; ++p) {
      const uint32_t old = tk[p];
      const uint32_t mx = old > cur ? old : cur;
      tk[p] = mx;
      cur = old > cur ? cur : old;
    }
  }
  cnt[rb_own] = 0;
  thrF = __uint_as_float((tk[15] & 0xFFFF8000u) ^ 0x80000000u);
}

// ------------------------------------------------------------------
__global__ void cvt_bf16_kernel(const float* __restrict__ in, bf16* __restrict__ out, int n4) {
  int i = blockIdx.x * blockDim.x + threadIdx.x;
  if (i >= n4) return;
  f32x4 v = *(const f32x4*)(in + (size_t)i * 4);
  bf16x4 o = {(bf16)v.x, (bf16)v.y, (bf16)v.z, (bf16)v.w};
  *(bf16x4*)(out + (size_t)i * 4) = o;
}

__global__ void transpose_f32_bf16(const float* __restrict__ in, bf16* __restrict__ out,
                                   int R, int C) {
  __shared__ float tile[32][33];
  const int c0 = blockIdx.x * 32, r0 = blockIdx.y * 32;
  for (int i = threadIdx.y; i < 32; i += 8)
    tile[i][threadIdx.x] = in[(size_t)(r0 + i) * C + c0 + threadIdx.x];
  __syncthreads();
  for (int i = threadIdx.y; i < 32; i += 8)
    out[(size_t)(c0 + i) * R + r0 + threadIdx.x] = (bf16)tile[threadIdx.x][i];
}

__global__ __launch_bounds__(256) void rownorm_kernel(const float* __restrict__ in,
                                                      bf16* __restrict__ out) {
  __shared__ float red[4];
  const int row = blockIdx.x, t = threadIdx.x;
  f32x4 v = *(const f32x4*)(in + (size_t)row * 1024 + t * 4);
  float sq = v.x * v.x + v.y * v.y + v.z * v.z + v.w * v.w;
  sq = block_sum(sq, red);
  float sc = rsqrtf(sq + 1e-8f);
  bf16x4 o = {(bf16)(v.x * sc), (bf16)(v.y * sc), (bf16)(v.z * sc), (bf16)(v.w * sc)};
  *(bf16x4*)(out + (size_t)row * 1024 + t * 4) = o;
}

// ------------------------------------------------------------------
// C = A @ B^T  (128x128 tile, BK=32).  EPI 0: fp32+bias.  EPI 1: silu gate -> bf16.
// Double-buffered LDS + counted vmcnt(4); swizzled stage/read. (64-reg acc ->
// no spill at this pressure; exercised+passed r1/r2.)
template <int EPI>
__global__ __launch_bounds__(256, 2) void gemm_bt_kernel(
    const bf16* __restrict__ A, const bf16* __restrict__ Bm, int Kd,
    float* __restrict__ Cf, bf16* __restrict__ Cb,
    const float* __restrict__ bias, const float* __restrict__ conf,
    const float* __restrict__ w1c) {
  __shared__ bf16 As0[128 * 32];
  __shared__ bf16 As1[128 * 32];
  __shared__ bf16 Bs0[128 * 32];
  __shared__ bf16 Bs1[128 * 32];
  const int tid = threadIdx.x;
  const int lane = tid & 63, wave = tid >> 6;
  const int wr = (wave >> 1) * 64, wc = (wave & 1) * 64;
  const int m0 = blockIdx.x * 128, n0 = blockIdx.y * 128;
  const int ar = lane & 15;
  const int sw8 = (((lane >> 4) ^ ((ar >> 1) & 3)) << 3);  // swizzled chunk, elems

  f32x4 acc[4][4];
#pragma unroll
  for (int i = 0; i < 4; ++i)
#pragma unroll
    for (int j = 0; j < 4; ++j) acc[i][j] = (f32x4){0.f, 0.f, 0.f, 0.f};

  const bf16 *Ac = As0, *An = As1, *Bc = Bs0, *Bn = Bs1;
  const int NT = Kd >> 5;
  stage_tile(A + (size_t)m0 * Kd, Kd, (bf16*)Ac, tid);
  stage_tile(Bm + (size_t)n0 * Kd, Kd, (bf16*)Bc, tid);

  for (int T = 0; T < NT; ++T) {
    if (T + 1 < NT) {
      stage_tile(A + (size_t)m0 * Kd + (T + 1) * 32, Kd, (bf16*)An, tid);
      stage_tile(Bm + (size_t)n0 * Kd + (T + 1) * 32, Kd, (bf16*)Bn, tid);
      asm volatile("s_waitcnt vmcnt(4)" ::: "memory");   // tile T landed; T+1 in flight
    } else {
      asm volatile("s_waitcnt vmcnt(0)" ::: "memory");
    }
    __builtin_amdgcn_s_barrier();
    bf16x8 af[4], bfr[4];
#pragma unroll
    for (int i = 0; i < 4; ++i)
      af[i] = *(const bf16x8*)(Ac + (wr + i * 16 + ar) * 32 + sw8);
#pragma unroll
    for (int j = 0; j < 4; ++j)
      bfr[j] = *(const bf16x8*)(Bc + (wc + j * 16 + ar) * 32 + sw8);
#pragma unroll
    for (int i = 0; i < 4; ++i)
#pragma unroll
      for (int j = 0; j < 4; ++j)
        acc[i][j] = mfma_bf16(af[i], bfr[j], acc[i][j]);
    asm volatile("s_waitcnt lgkmcnt(0)" ::: "memory");   // reads of cur buf done
    __builtin_amdgcn_s_barrier();                        // before T+2 overwrites it
    const bf16* t0 = Ac; Ac = An; An = t0;
    const bf16* t1 = Bc; Bc = Bn; Bn = t1;
  }

  const int mq = (lane >> 4) * 4, nq = lane & 15;
#pragma unroll
  for (int i = 0; i < 4; ++i)
#pragma unroll
    for (int j = 0; j < 4; ++j)
#pragma unroll
      for (int r = 0; r < 4; ++r) {
        const int m = m0 + wr + i * 16 + mq + r;
        const int n = n0 + wc + j * 16 + nq;
        float x = acc[i][j][r];
        if (EPI == 0) {
          Cf[(size_t)m * 1024 + n] = x + bias[n];
        } else {
          x += bias[n] + conf[m] * w1c[n];
          x = x / (1.f + expf(-x));   // silu
          Cb[(size_t)m * 1024 + n] = (bf16)x;
        }
      }
}

// ------------------------------------------------------------------
// sims = kn @ mn^T with register-direct top-16.
// r0 structure EXACTLY (single-buffered tiles, __syncthreads 2-barrier k-loop,
// scan outside the k-loop: no pipeline state live at the register-max point ->
// no spill; r0 measured WRITE_SIZE 20MB) + r2's validated XOR swizzle on
// stage/read (bank conflicts 5.6e7 -> 6.6e6). dbuf deliberately NOT used here:
// r1/r2 proved it spills ~600-800MB at this register pressure and loses 300+ us.
__global__ __launch_bounds__(256, 2) void sims_topk_kernel(
    const bf16* __restrict__ kn, const bf16* __restrict__ mn,
    uint32_t* __restrict__ tpk) {
  __shared__ bf16 As[128 * 32];        // 8 KB
  __shared__ bf16 Bs0[128 * 32];       // 8 KB
  __shared__ bf16 Bs1[128 * 32];       // 8 KB
  __shared__ uint32_t cand[256 * CAP]; // 49 KB: 128 rows x 2 col-halves
  __shared__ int cnt[256];             // 1 KB

  const int tid = threadIdx.x;
  const int lane = tid & 63, wave = tid >> 6;
  const int wr = (wave >> 1) * 64;     // wave's row base (block-local)
  const int ch = wave & 1;             // wave's col-half of the 128-wide N-tile
  const int split = blockIdx.x;        // grid (8,64): linear%8==split -> XCD affinity
  const int m0 = blockIdx.y * 128;
  const int sbeg = split * SLOTS_PER;
  const int ar = lane & 15;
  const int sw8 = (((lane >> 4) ^ ((ar >> 1) & 3)) << 3);  // swizzled chunk, elems
  const int mq = (lane >> 4) * 4, nq = lane & 15;
  const int rb_own = (wr + lane) * 2 + ch;   // this lane's candidate list

  cnt[tid] = 0;

  uint32_t tk[16];
#pragma unroll
  for (int j = 0; j < 16; ++j) tk[j] = 0u;
  float thrF = __uint_as_float(0x80000000u);  // -0.0f: only positives push

  for (int it = 0; it < SLOTS_PER / 256; ++it) {   // 16 iters x 256 slots
    f32x4 acc[2][4][4];
#pragma unroll
    for (int c = 0; c < 2; ++c)
#pragma unroll
      for (int i = 0; i < 4; ++i)
#pragma unroll
        for (int j = 0; j < 4; ++j) acc[c][i][j] = (f32x4){0.f, 0.f, 0.f, 0.f};

    const int n0 = sbeg + it * 256;
    for (int k0 = 0; k0 < 1024; k0 += 32) {
      __syncthreads();   // also orders first-iter cnt init & prior scans vs staging
      stage_tile(kn + (size_t)m0 * 1024 + k0, 1024, As, tid);
      stage_tile(mn + (size_t)n0 * 1024 + k0, 1024, Bs0, tid);
      stage_tile(mn + (size_t)(n0 + 128) * 1024 + k0, 1024, Bs1, tid);
      __syncthreads();
      bf16x8 af[4], b0[4], b1[4];
#pragma unroll
      for (int i = 0; i < 4; ++i)
        af[i] = *(const bf16x8*)(As + (wr + i * 16 + ar) * 32 + sw8);
#pragma unroll
      for (int j = 0; j < 4; ++j) {
        b0[j] = *(const bf16x8*)(Bs0 + (ch * 64 + j * 16 + ar) * 32 + sw8);
        b1[j] = *(const bf16x8*)(Bs1 + (ch * 64 + j * 16 + ar) * 32 + sw8);
      }
#pragma unroll
      for (int i = 0; i < 4; ++i)
#pragma unroll
        for (int j = 0; j < 4; ++j) {
          acc[0][i][j] = mfma_bf16(af[i], b0[j], acc[0][i][j]);
          acc[1][i][j] = mfma_bf16(af[i], b1[j], acc[1][i][j]);
        }
    }

    // register-direct scan of both 128-slot chunks (no barriers)
#pragma unroll
    for (int cc = 0; cc < 2; ++cc) {
      const int colbase = sbeg + it * 256 + cc * 128 + ch * 64;
      uint64_t skip = 0ull;
#pragma unroll
      for (int i = 0; i < 4; ++i)
#pragma unroll
        for (int r = 0; r < 4; ++r) {
          const int owner = i * 16 + mq + r;               // 0..63 (lane id)
          const float thr = __shfl(thrF, owner, 64);
          const int rb = (wr + owner) * 2 + ch;
#pragma unroll
          for (int j = 0; j < 4; ++j) {
            const float v = acc[cc][i][j][r];
            if (v > thr) {
              const int old = atomicAdd(&cnt[rb], 1);
              if (old < CAP) cand[rb * CAP + old] = pack_key(v, colbase + j * 16 + nq);
              else skip |= (1ull << (i * 16 + r * 4 + j));
            }
          }
        }
      drain_merge(cand, cnt, rb_own, tk, thrF);
      if (__any(skip != 0ull)) {   // rare: overflow rescan (bounded <=15 pushes/list)
#pragma unroll
        for (int i = 0; i < 4; ++i)
#pragma unroll
          for (int r = 0; r < 4; ++r) {
            const int owner = i * 16 + mq + r;
            const float thr = __shfl(thrF, owner, 64);
            const int rb = (wr + owner) * 2 + ch;
#pragma unroll
            for (int j = 0; j < 4; ++j) {
              if (skip & (1ull << (i * 16 + r * 4 + j))) {
                const float v = acc[cc][i][j][r];
                if (v > thr) {
                  const int old = atomicAdd(&cnt[rb], 1);
                  if (old < CAP) cand[rb * CAP + old] = pack_key(v, colbase + j * 16 + nq);
                }
              }
            }
          }
        drain_merge(cand, cnt, rb_own, tk, thrF);
      }
    }
  }

  // emit: [row][split][half][16] -> 256 candidates per row
  const int row = m0 + wr + lane;
  uint32_t* dst = tpk + (((size_t)row * NSPLIT + split) * 2 + ch) * 16;
#pragma unroll
  for (int j = 0; j < 16; ++j) dst[j] = tk[j];
}

// ------------------------------------------------------------------
// merge 256 candidate keys -> top-16, softmax, weighted gather of vals
__global__ __launch_bounds__(256) void merge_pred_kernel(
    const uint32_t* __restrict__ tpk, const float* __restrict__ vals,
    float* __restrict__ pred, float* __restrict__ conf) {
  __shared__ uint32_t ks[256];
  __shared__ float sv[16];
  __shared__ int si[16];
  __shared__ float sw[16];
  const int row = blockIdx.x, t = threadIdx.x;
  const uint32_t k = tpk[(size_t)row * 256 + t];
  ks[t] = k;
  __syncthreads();
  int rank = 0;
  for (int j = 0; j < 256; ++j) rank += (ks[j] > k);   // keys unique (slot bits)
  if (rank < 16) {
    sv[rank] = __uint_as_float((k & 0xFFFF8000u) ^ 0x80000000u);
    si[rank] = (int)(k & 0x7FFFu);
  }
  __syncthreads();
  if (t == 0) {
    const float m = sv[0];
    float s = 0.f;
#pragma unroll
    for (int q = 0; q < 16; ++q) {
      float e = expf((sv[q] - m) * 10.f);   // 1/TEMP
      sw[q] = e;
      s += e;
    }
    const float inv = 1.f / s;
#pragma unroll
    for (int q = 0; q < 16; ++q) sw[q] *= inv;
    conf[row] = (m + 1.f) * 0.5f;
  }
  __syncthreads();
  const int col = t * 4;
  f32x4 a = (f32x4){0.f, 0.f, 0.f, 0.f};
#pragma unroll
  for (int q = 0; q < 16; ++q) {
    f32x4 vv = *(const f32x4*)(vals + (size_t)si[q] * 1024 + col);
    a += vv * sw[q];
  }
  *(f32x4*)(pred + (size_t)row * 1024 + col) = a;
}

// ------------------------------------------------------------------
__global__ __launch_bounds__(256) void feats_kernel(
    const float* __restrict__ h, const float* __restrict__ pred,
    const float* __restrict__ gin, const float* __restrict__ bin,
    const float* __restrict__ gpr, const float* __restrict__ bpr,
    bf16* __restrict__ feats) {
  __shared__ float red[4];
  const int row = blockIdx.x, t = threadIdx.x;
  {
    f32x4 v = *(const f32x4*)(h + (size_t)row * 1024 + t * 4);
    float s = v.x + v.y + v.z + v.w;
    float sq = v.x * v.x + v.y * v.y + v.z * v.z + v.w * v.w;
    s = block_sum(s, red);
    sq = block_sum(sq, red);
    const float mean = s * (1.f / 1024.f);
    const float rstd = rsqrtf(sq * (1.f / 1024.f) - mean * mean + 1e-5f);
    f32x4 g = *(const f32x4*)(gin + t * 4);
    f32x4 b = *(const f32x4*)(bin + t * 4);
    bf16x4 o = {(bf16)((v.x - mean) * rstd * g.x + b.x),
                (bf16)((v.y - mean) * rstd * g.y + b.y),
                (bf16)((v.z - mean) * rstd * g.z + b.z),
                (bf16)((v.w - mean) * rstd * g.w + b.w)};
    *(bf16x4*)(feats + (size_t)row * 2048 + t * 4) = o;
  }
  {
    f32x4 v = *(const f32x4*)(pred + (size_t)row * 1024 + t * 4);
    float s = v.x + v.y + v.z + v.w;
    float sq = v.x * v.x + v.y * v.y + v.z * v.z + v.w * v.w;
    s = block_sum(s, red);
    sq = block_sum(sq, red);
    const float mean = s * (1.f / 1024.f);
    const float rstd = rsqrtf(sq * (1.f / 1024.f) - mean * mean + 1e-5f);
    f32x4 g = *(const f32x4*)(gpr + t * 4);
    f32x4 b = *(const f32x4*)(bpr + t * 4);
    bf16x4 o = {(bf16)((v.x - mean) * rstd * g.x + b.x),
                (bf16)((v.y - mean) * rstd * g.y + b.y),
                (bf16)((v.z - mean) * rstd * g.z + b.z),
                (bf16)((v.w - mean) * rstd * g.w + b.w)};
    *(bf16x4*)(feats + (size_t)row * 2048 + 1024 + t * 4) = o;
  }
}

// ------------------------------------------------------------------
__global__ __launch_bounds__(256) void final_kernel(
    const bf16* __restrict__ hmid, const float* __restrict__ W2,
    const float* __restrict__ b2, const float* __restrict__ h,
    const float* __restrict__ pred, const float* __restrict__ conf,
    float* __restrict__ out) {
  __shared__ float red[4];
  const int row = blockIdx.x, t = threadIdx.x;
  float s = 0.f;
#pragma unroll
  for (int j = 0; j < 4; ++j) {
    const int c = t + 256 * j;
    s += (float)hmid[(size_t)row * 1024 + c] * W2[c];
  }
  s = block_sum(s, red);
  float alpha = 1.f / (1.f + expf(-(s + b2[0])));
  alpha = fminf(fmaxf(alpha, 0.f), 1.f);
  f32x4 hv = *(const f32x4*)(h + (size_t)row * 1024 + t * 4);
  f32x4 pv = *(const f32x4*)(pred + (size_t)row * 1024 + t * 4);
  f32x4 y = hv + pv * alpha;
  *(f32x4*)(out + (size_t)row * 1024 + t * 4) = y;
  if (t == 0) {
    atomicAdd(out + 8388608, alpha * (1.f / 8192.f));
    atomicAdd(out + 8388609, conf[row] * (1.f / 8192.f));
  }
}

// ------------------------------------------------------------------
extern "C" void kernel_launch(void* const* d_in, const int* in_sizes, int n_in,
                              void* d_out, int out_size, void* d_ws, size_t ws_size,
                              hipStream_t stream) {
  const float* h_in      = (const float*)d_in[0];
  const float* Wk        = (const float*)d_in[1];
  const float* bk        = (const float*)d_in[2];
  const float* cube_keys = (const float*)d_in[3];
  const float* cube_vals = (const float*)d_in[4];
  const float* ln_in_g   = (const float*)d_in[5];
  const float* ln_in_b   = (const float*)d_in[6];
  const float* ln_pred_g = (const float*)d_in[7];
  const float* ln_pred_b = (const float*)d_in[8];
  const float* W1        = (const float*)d_in[9];
  const float* b1        = (const float*)d_in[10];
  const float* W2        = (const float*)d_in[11];
  const float* b2        = (const float*)d_in[12];

  char* ws = (char*)d_ws;
  bf16*     mn    = (bf16*)(ws + WS_MN);
  float*    pred  = (float*)(ws + WS_PRED);
  bf16*     h_bf  = (bf16*)(ws + WS_HBF);
  bf16*     hmid  = (bf16*)(ws + WS_HMID);
  bf16*     wkT   = (bf16*)(ws + WS_WKT);
  bf16*     w1T   = (bf16*)(ws + WS_W1T);
  float*    keys  = (float*)(ws + WS_KEYS);
  bf16*     feats = (bf16*)(ws + WS_FEATS);
  bf16*     kn    = (bf16*)(ws + WS_KN);
  uint32_t* tpk   = (uint32_t*)(ws + WS_TPK);
  float*    conf  = (float*)(ws + WS_CONF);
  float*    out   = (float*)d_out;
  const float* w1c = W1 + (size_t)2048 * 1024;  // conf row of W1

  cvt_bf16_kernel<<<(BL * DDIM / 4 + 255) / 256, 256, 0, stream>>>(h_in, h_bf, BL * DDIM / 4);
  transpose_f32_bf16<<<dim3(32, 32), dim3(32, 8), 0, stream>>>(Wk, wkT, 1024, 1024);
  transpose_f32_bf16<<<dim3(32, 64), dim3(32, 8), 0, stream>>>(W1, w1T, 2048, 1024);
  rownorm_kernel<<<NSLOTS, 256, 0, stream>>>(cube_keys, mn);

  gemm_bt_kernel<0><<<dim3(64, 8), 256, 0, stream>>>(h_bf, wkT, 1024, keys, nullptr,
                                                     bk, nullptr, nullptr);
  rownorm_kernel<<<BL, 256, 0, stream>>>(keys, kn);

  // fused sims GEMM + register-direct top-16
  sims_topk_kernel<<<dim3(NSPLIT, 64), 256, 0, stream>>>(kn, mn, tpk);

  merge_pred_kernel<<<BL, 256, 0, stream>>>(tpk, cube_vals, pred, conf);

  feats_kernel<<<BL, 256, 0, stream>>>(h_in, pred, ln_in_g, ln_in_b,
                                       ln_pred_g, ln_pred_b, feats);
  gemm_bt_kernel<1><<<dim3(64, 8), 256, 0, stream>>>(feats, w1T, 2048, nullptr, hmid,
                                                     b1, conf, w1c);

  hipMemsetAsync(out + 8388608, 0, 8, stream);
  final_kernel<<<BL, 256, 0, stream>>>(hmid, W2, b2, h_in, pred, conf, out);
}